// Round 3
// baseline (430.601 us; speedup 1.0000x reference)
//
#include <hip/hip_runtime.h>
#include <hip/hip_bf16.h>
#include <math.h>

#define N_AGENTS 8192
#define LATENT   128
#define HIDDEN   32
#define MSG      64
#define CONCAT   96      // HIDDEN + MSG
#define THRESH   1.5f
#define KSPLIT   16      // K split into 16 slices of 512
#define SLICE    (N_AGENTS / KSPLIT)   // 512
#define SGRP     4       // slice-groups: 4 slices (one per wave) per block

typedef float f32x4  __attribute__((ext_vector_type(4)));
typedef short bf16x8 __attribute__((ext_vector_type(8)));  // 8 bf16 in 4 VGPRs

// ---------------- JAX threefry2x32, key = (0, 42) ----------------
__device__ __forceinline__ unsigned rotl32(unsigned x, unsigned r) {
  return (x << r) | (x >> (32u - r));
}
__device__ __forceinline__ void tf_round(unsigned &x0, unsigned &x1, unsigned r) {
  x0 += x1; x1 = rotl32(x1, r); x1 ^= x0;
}
__device__ __forceinline__ uint2 threefry_0_42(unsigned x0, unsigned x1) {
  const unsigned k0 = 0u, k1 = 42u, k2 = 0x1BD11BDAu ^ 0u ^ 42u;
  x0 += k0; x1 += k1;
  tf_round(x0,x1,13); tf_round(x0,x1,15); tf_round(x0,x1,26); tf_round(x0,x1, 6);
  x0 += k1; x1 += k2 + 1u;
  tf_round(x0,x1,17); tf_round(x0,x1,29); tf_round(x0,x1,16); tf_round(x0,x1,24);
  x0 += k2; x1 += k0 + 2u;
  tf_round(x0,x1,13); tf_round(x0,x1,15); tf_round(x0,x1,26); tf_round(x0,x1, 6);
  x0 += k0; x1 += k1 + 3u;
  tf_round(x0,x1,17); tf_round(x0,x1,29); tf_round(x0,x1,16); tf_round(x0,x1,24);
  x0 += k1; x1 += k2 + 4u;
  tf_round(x0,x1,13); tf_round(x0,x1,15); tf_round(x0,x1,26); tf_round(x0,x1, 6);
  x0 += k2; x1 += k0 + 5u;
  return make_uint2(x0, x1);
}

__device__ __forceinline__ float gumbel_at(unsigned idx) {
  const unsigned H = (N_AGENTS * MSG) / 2; // 262144
  unsigned bits;
  if (idx < H) {                  // wave-uniform (idx ranges are 64-aligned)
    uint2 o = threefry_0_42(idx, idx + H);
    bits = o.x;
  } else {
    uint2 o = threefry_0_42(idx - H, idx);
    bits = o.y;
  }
  float f = __uint_as_float((bits >> 9) | 0x3f800000u) - 1.0f;
  float u = fmaxf(1e-10f, f + 1e-10f);
  return -logf(-logf(u));
}

__device__ __forceinline__ unsigned short f2bf(float x) { // RNE f32 -> bf16
  unsigned u = __float_as_uint(x);
  u += 0x7FFFu + ((u >> 16) & 1u);
  return (unsigned short)(u >> 16);
}

// ---------------- Kernel A: h = relu(zW+b); messages bf16 row-major + transposed ----
__global__ __launch_bounds__(256) void k_encode(
    const float* __restrict__ z, const float* __restrict__ encW, const float* __restrict__ encB,
    const float* __restrict__ msgW, const float* __restrict__ msgB,
    float* __restrict__ h_out, unsigned* __restrict__ msgR_u32,
    unsigned short* __restrict__ msgT)
{
  __shared__ float z_s[8][LATENT];
  __shared__ float encW_s[LATENT*HIDDEN];
  __shared__ float msgW_s[HIDDEN*MSG];
  __shared__ float h_s[8][HIDDEN];
  __shared__ float m_s[8][MSG];
  const int t  = threadIdx.x;
  const int r0 = blockIdx.x * 8;

  #pragma unroll
  for (int it = 0; it < 16; ++it) encW_s[t + 256*it] = encW[t + 256*it];
  #pragma unroll
  for (int it = 0; it < 8; ++it)  msgW_s[t + 256*it] = msgW[t + 256*it];
  #pragma unroll
  for (int it = 0; it < 4; ++it) {
    int q = t + 256*it;
    z_s[q >> 7][q & 127] = z[(size_t)r0*LATENT + q];
  }
  __syncthreads();

  { // h: 8 rows x 32 cols
    int r = t >> 5, c = t & 31;
    float acc = encB[c];
    #pragma unroll
    for (int k = 0; k < LATENT; ++k) acc = fmaf(z_s[r][k], encW_s[k*HIDDEN + c], acc);
    float hv = fmaxf(acc, 0.0f);
    h_s[r][c] = hv;
    h_out[(size_t)(r0 + r)*HIDDEN + c] = hv;
  }
  __syncthreads();

  #pragma unroll
  for (int it = 0; it < 2; ++it) { // messages: 8 rows x 64 cols
    int r = (t >> 6) + 4*it, c = t & 63;
    float acc = msgB[c];
    #pragma unroll
    for (int k = 0; k < HIDDEN; ++k) acc = fmaf(h_s[r][k], msgW_s[k*MSG + c], acc);
    m_s[r][c] = acc;
  }
  __syncthreads();

  { // msgR (row-major bf16, packed u32)
    int r = t >> 5, c0 = (t & 31) * 2;
    unsigned lo = f2bf(m_s[r][c0]), hi = f2bf(m_s[r][c0 + 1]);
    msgR_u32[(size_t)(r0 + r)*32 + (t & 31)] = lo | (hi << 16);
  }
  { // msgT (transposed bf16 [64][8192])
    int c = t & 63, rr = (t >> 6) * 2;
    unsigned lo = f2bf(m_s[rr][c]), hi = f2bf(m_s[rr + 1][c]);
    *(unsigned*)(msgT + (size_t)c*N_AGENTS + r0 + rr) = lo | (hi << 16);
  }
}

// ---------------- Kernel B: P[g] = adj @ msg partials via bf16 MFMA, no atomics ----
// Block: 4 waves share one 32-row tile; wave wv handles K-slice sliceGrp*4+wv.
// Cross-wave reduce in LDS, then plain dwordx4 stores into partial buffer P[sliceGrp].
// mfma_f32_16x16x32_bf16 layouts (verified R1): A[m=lane&15][k=(lane>>4)*8+j],
// B[k=(lane>>4)*8+j][n=lane&15], C/D: col=lane&15, row=(lane>>4)*4+reg.
__device__ __forceinline__ bf16x8 adj_frag(f32x4 lo, f32x4 hi) {
  union { bf16x8 v; unsigned u[4]; } r;
  r.u[0] = (lo.x < THRESH ? 0x3F80u : 0u) | (lo.y < THRESH ? 0x3F800000u : 0u);
  r.u[1] = (lo.z < THRESH ? 0x3F80u : 0u) | (lo.w < THRESH ? 0x3F800000u : 0u);
  r.u[2] = (hi.x < THRESH ? 0x3F80u : 0u) | (hi.y < THRESH ? 0x3F800000u : 0u);
  r.u[3] = (hi.z < THRESH ? 0x3F80u : 0u) | (hi.w < THRESH ? 0x3F800000u : 0u);
  return r.v;
}

__global__ __launch_bounds__(256, 4) void k_agg(
    const float* __restrict__ dists, const unsigned short* __restrict__ msgT,
    float* __restrict__ P)
{
  __shared__ float red_s[4][32][MSG];           // 32 KB
  const int lane = threadIdx.x & 63;
  const int wv   = threadIdx.x >> 6;
  const int rowTile  = blockIdx.x & 255;        // 256 row tiles of 32
  const int sliceGrp = blockIdx.x >> 8;         // 0..3
  const int row0 = rowTile * 32;
  const int k0   = (sliceGrp * 4 + wv) * SLICE; // wave-private 512-wide K chunk
  const int m = lane & 15, q = lane >> 4;

  const float* a0p = dists + (size_t)(row0 + m) * N_AGENTS + k0 + q*8;
  const float* a1p = a0p + (size_t)16 * N_AGENTS;
  const unsigned short* b0p = msgT + (size_t)(m)      * N_AGENTS + k0 + q*8;
  const unsigned short* b1p = msgT + (size_t)(m + 16) * N_AGENTS + k0 + q*8;
  const unsigned short* b2p = msgT + (size_t)(m + 32) * N_AGENTS + k0 + q*8;
  const unsigned short* b3p = msgT + (size_t)(m + 48) * N_AGENTS + k0 + q*8;

  f32x4 acc[2][4];
  #pragma unroll
  for (int g = 0; g < 2; ++g)
    #pragma unroll
    for (int nt = 0; nt < 4; ++nt) acc[g][nt] = (f32x4)0.0f;

  #pragma unroll
  for (int kk = 0; kk < SLICE / 32; ++kk) {     // 16 iterations, K-step 32
    const int off = kk * 32;
    f32x4 a00 = __builtin_nontemporal_load((const f32x4*)(a0p + off));
    f32x4 a01 = __builtin_nontemporal_load((const f32x4*)(a0p + off + 4));
    f32x4 a10 = __builtin_nontemporal_load((const f32x4*)(a1p + off));
    f32x4 a11 = __builtin_nontemporal_load((const f32x4*)(a1p + off + 4));
    bf16x8 b0 = *(const bf16x8*)(b0p + off);
    bf16x8 b1 = *(const bf16x8*)(b1p + off);
    bf16x8 b2 = *(const bf16x8*)(b2p + off);
    bf16x8 b3 = *(const bf16x8*)(b3p + off);
    bf16x8 af0 = adj_frag(a00, a01);
    bf16x8 af1 = adj_frag(a10, a11);
    acc[0][0] = __builtin_amdgcn_mfma_f32_16x16x32_bf16(af0, b0, acc[0][0], 0, 0, 0);
    acc[0][1] = __builtin_amdgcn_mfma_f32_16x16x32_bf16(af0, b1, acc[0][1], 0, 0, 0);
    acc[0][2] = __builtin_amdgcn_mfma_f32_16x16x32_bf16(af0, b2, acc[0][2], 0, 0, 0);
    acc[0][3] = __builtin_amdgcn_mfma_f32_16x16x32_bf16(af0, b3, acc[0][3], 0, 0, 0);
    acc[1][0] = __builtin_amdgcn_mfma_f32_16x16x32_bf16(af1, b0, acc[1][0], 0, 0, 0);
    acc[1][1] = __builtin_amdgcn_mfma_f32_16x16x32_bf16(af1, b1, acc[1][1], 0, 0, 0);
    acc[1][2] = __builtin_amdgcn_mfma_f32_16x16x32_bf16(af1, b2, acc[1][2], 0, 0, 0);
    acc[1][3] = __builtin_amdgcn_mfma_f32_16x16x32_bf16(af1, b3, acc[1][3], 0, 0, 0);
  }

  // dump accumulators to LDS in (row, col) layout
  #pragma unroll
  for (int g = 0; g < 2; ++g)
    #pragma unroll
    for (int nt = 0; nt < 4; ++nt)
      #pragma unroll
      for (int r = 0; r < 4; ++r)
        red_s[wv][g*16 + q*4 + r][nt*16 + m] = acc[g][nt][r];
  __syncthreads();

  // cross-wave sum: thread t owns 8 consecutive floats of the 32x64 tile
  const int row = threadIdx.x >> 3;             // 0..31
  const int c0  = (threadIdx.x & 7) * 8;        // 0..56
  f32x4 s0 = *(const f32x4*)&red_s[0][row][c0];
  f32x4 s1 = *(const f32x4*)&red_s[0][row][c0 + 4];
  #pragma unroll
  for (int w2 = 1; w2 < 4; ++w2) {
    s0 += *(const f32x4*)&red_s[w2][row][c0];
    s1 += *(const f32x4*)&red_s[w2][row][c0 + 4];
  }
  float* dst = P + ((size_t)sliceGrp * N_AGENTS + row0 + row) * MSG + c0;
  *(f32x4*)dst       = s0;
  *(f32x4*)(dst + 4) = s1;
}

// ---------------- Kernel C: epilogue — partial sum, diag fix, MLP, gumbel softmax ----
__global__ __launch_bounds__(256) void k_out(
    const float* __restrict__ P, const float* __restrict__ dists,
    const unsigned short* __restrict__ msgR,
    const float* __restrict__ h_in,
    const float* __restrict__ updW, const float* __restrict__ updB,
    const float* __restrict__ outW, const float* __restrict__ outB,
    const float* __restrict__ tau, float* __restrict__ out)
{
  __shared__ float x_s[4][CONCAT];
  __shared__ float h2_s[4][HIDDEN];
  const int w    = threadIdx.x >> 6;
  const int lane = threadIdx.x & 63;
  const int i    = blockIdx.x * 4 + w;

  float agg = 0.0f;
  #pragma unroll
  for (int g = 0; g < SGRP; ++g)
    agg += P[((size_t)g * N_AGENTS + i) * MSG + lane];

  float dii = dists[(size_t)i * (N_AGENTS + 1)];
  if (dii < THRESH) { // remove diagonal contribution (adj has zero diagonal)
    unsigned short us = msgR[(size_t)i * MSG + lane];
    agg -= __uint_as_float(((unsigned)us) << 16);
  }

  x_s[w][HIDDEN + lane] = agg;
  if (lane < HIDDEN) x_s[w][lane] = h_in[(size_t)i * HIDDEN + lane];
  __syncthreads();

  if (lane < HIDDEN) {
    float acc = updB[lane];
    #pragma unroll
    for (int k = 0; k < CONCAT; ++k) acc = fmaf(x_s[w][k], updW[k*HIDDEN + lane], acc);
    h2_s[w][lane] = fmaxf(acc, 0.0f);
  }
  __syncthreads();

  float lg = outB[lane];
  #pragma unroll
  for (int c = 0; c < HIDDEN; ++c) lg = fmaf(h2_s[w][c], outW[c*MSG + lane], lg);

  float tv = (lg + gumbel_at((unsigned)i*64u + (unsigned)lane)) / tau[0];

  float mx = tv;
  #pragma unroll
  for (int off = 32; off > 0; off >>= 1) mx = fmaxf(mx, __shfl_xor(mx, off, 64));
  float ex = expf(tv - mx);
  float sm = ex;
  #pragma unroll
  for (int off = 32; off > 0; off >>= 1) sm += __shfl_xor(sm, off, 64);
  out[(size_t)i * MSG + lane] = ex / sm;
}

extern "C" void kernel_launch(void* const* d_in, const int* in_sizes, int n_in,
                              void* d_out, int out_size, void* d_ws, size_t ws_size,
                              hipStream_t stream) {
  const float* z     = (const float*)d_in[0];
  const float* tau   = (const float*)d_in[1];
  const float* dists = (const float*)d_in[2];
  const float* encW  = (const float*)d_in[3];
  const float* encB  = (const float*)d_in[4];
  const float* msgW  = (const float*)d_in[5];
  const float* msgB  = (const float*)d_in[6];
  const float* updW  = (const float*)d_in[7];
  const float* updB  = (const float*)d_in[8];
  const float* outW  = (const float*)d_in[9];
  const float* outB  = (const float*)d_in[10];
  (void)in_sizes; (void)n_in; (void)out_size; (void)ws_size;

  char* ws = (char*)d_ws;
  float*          P_ws  = (float*)(ws);                      // 4*8192*64*4 = 8 MB
  float*          h_ws  = (float*)(ws + (8u<<20));           // 8192*32*4   = 1 MB
  unsigned short* msgR  = (unsigned short*)(ws + (9u<<20));  // 8192*64*2   = 1 MB
  unsigned short* msgT  = (unsigned short*)(ws + (10u<<20)); // 64*8192*2   = 1 MB
  float* out = (float*)d_out;

  hipLaunchKernelGGL(k_encode, dim3(N_AGENTS/8), dim3(256), 0, stream,
                     z, encW, encB, msgW, msgB, h_ws, (unsigned*)msgR, msgT);
  hipLaunchKernelGGL(k_agg, dim3(256 * SGRP), dim3(256), 0, stream,
                     dists, msgT, P_ws);
  hipLaunchKernelGGL(k_out, dim3(N_AGENTS/4), dim3(256), 0, stream,
                     P_ws, dists, msgR, h_ws, updW, updB, outW, outB, tau, out);
}

// Round 4
// 420.077 us; speedup vs baseline: 1.0251x; 1.0251x over previous
//
#include <hip/hip_runtime.h>
#include <hip/hip_bf16.h>
#include <math.h>

#define N_AGENTS 8192
#define LATENT   128
#define HIDDEN   32
#define MSG      64
#define CONCAT   96      // HIDDEN + MSG
#define THRESH   1.5f
#define NPART    16      // 4 sliceGrp blocks x 4 waves = 16 K-partials
#define ROWSTRIDE 260    // LDS row stride in floats (+4 pad: 4-bank rotation/row)

typedef float f32x4  __attribute__((ext_vector_type(4)));
typedef short bf16x8 __attribute__((ext_vector_type(8)));  // 8 bf16 in 4 VGPRs

// ---------------- JAX threefry2x32, key = (0, 42) ----------------
__device__ __forceinline__ unsigned rotl32(unsigned x, unsigned r) {
  return (x << r) | (x >> (32u - r));
}
__device__ __forceinline__ void tf_round(unsigned &x0, unsigned &x1, unsigned r) {
  x0 += x1; x1 = rotl32(x1, r); x1 ^= x0;
}
__device__ __forceinline__ uint2 threefry_0_42(unsigned x0, unsigned x1) {
  const unsigned k0 = 0u, k1 = 42u, k2 = 0x1BD11BDAu ^ 0u ^ 42u;
  x0 += k0; x1 += k1;
  tf_round(x0,x1,13); tf_round(x0,x1,15); tf_round(x0,x1,26); tf_round(x0,x1, 6);
  x0 += k1; x1 += k2 + 1u;
  tf_round(x0,x1,17); tf_round(x0,x1,29); tf_round(x0,x1,16); tf_round(x0,x1,24);
  x0 += k2; x1 += k0 + 2u;
  tf_round(x0,x1,13); tf_round(x0,x1,15); tf_round(x0,x1,26); tf_round(x0,x1, 6);
  x0 += k0; x1 += k1 + 3u;
  tf_round(x0,x1,17); tf_round(x0,x1,29); tf_round(x0,x1,16); tf_round(x0,x1,24);
  x0 += k1; x1 += k2 + 4u;
  tf_round(x0,x1,13); tf_round(x0,x1,15); tf_round(x0,x1,26); tf_round(x0,x1, 6);
  x0 += k2; x1 += k0 + 5u;
  return make_uint2(x0, x1);
}

__device__ __forceinline__ float gumbel_at(unsigned idx) {
  const unsigned H = (N_AGENTS * MSG) / 2; // 262144
  unsigned bits;
  if (idx < H) {                  // wave-uniform (idx ranges are 64-aligned)
    uint2 o = threefry_0_42(idx, idx + H);
    bits = o.x;
  } else {
    uint2 o = threefry_0_42(idx - H, idx);
    bits = o.y;
  }
  float f = __uint_as_float((bits >> 9) | 0x3f800000u) - 1.0f;
  float u = fmaxf(1e-10f, f + 1e-10f);
  return -logf(-logf(u));
}

__device__ __forceinline__ unsigned short f2bf(float x) { // RNE f32 -> bf16
  unsigned u = __float_as_uint(x);
  u += 0x7FFFu + ((u >> 16) & 1u);
  return (unsigned short)(u >> 16);
}

// async global -> LDS, 16 B per lane; lane l's data lands at lds base + l*16
__device__ __forceinline__ void stage16(const float* g, float* l) {
  __builtin_amdgcn_global_load_lds(
      (const __attribute__((address_space(1))) void*)g,
      (__attribute__((address_space(3))) void*)l, 16, 0, 0);
}

// ---------------- Kernel A: h = relu(zW+b); messages bf16 row-major + transposed ----
__global__ __launch_bounds__(256) void k_encode(
    const float* __restrict__ z, const float* __restrict__ encW, const float* __restrict__ encB,
    const float* __restrict__ msgW, const float* __restrict__ msgB,
    float* __restrict__ h_out, unsigned* __restrict__ msgR_u32,
    unsigned short* __restrict__ msgT)
{
  __shared__ float z_s[8][LATENT];
  __shared__ float encW_s[LATENT*HIDDEN];
  __shared__ float msgW_s[HIDDEN*MSG];
  __shared__ float h_s[8][HIDDEN];
  __shared__ float m_s[8][MSG];
  const int t  = threadIdx.x;
  const int r0 = blockIdx.x * 8;

  #pragma unroll
  for (int it = 0; it < 16; ++it) encW_s[t + 256*it] = encW[t + 256*it];
  #pragma unroll
  for (int it = 0; it < 8; ++it)  msgW_s[t + 256*it] = msgW[t + 256*it];
  #pragma unroll
  for (int it = 0; it < 4; ++it) {
    int q = t + 256*it;
    z_s[q >> 7][q & 127] = z[(size_t)r0*LATENT + q];
  }
  __syncthreads();

  { // h: 8 rows x 32 cols
    int r = t >> 5, c = t & 31;
    float acc = encB[c];
    #pragma unroll
    for (int k = 0; k < LATENT; ++k) acc = fmaf(z_s[r][k], encW_s[k*HIDDEN + c], acc);
    float hv = fmaxf(acc, 0.0f);
    h_s[r][c] = hv;
    h_out[(size_t)(r0 + r)*HIDDEN + c] = hv;
  }
  __syncthreads();

  #pragma unroll
  for (int it = 0; it < 2; ++it) { // messages: 8 rows x 64 cols
    int r = (t >> 6) + 4*it, c = t & 63;
    float acc = msgB[c];
    #pragma unroll
    for (int k = 0; k < HIDDEN; ++k) acc = fmaf(h_s[r][k], msgW_s[k*MSG + c], acc);
    m_s[r][c] = acc;
  }
  __syncthreads();

  { // msgR (row-major bf16, packed u32)
    int r = t >> 5, c0 = (t & 31) * 2;
    unsigned lo = f2bf(m_s[r][c0]), hi = f2bf(m_s[r][c0 + 1]);
    msgR_u32[(size_t)(r0 + r)*32 + (t & 31)] = lo | (hi << 16);
  }
  { // msgT (transposed bf16 [64][8192])
    int c = t & 63, rr = (t >> 6) * 2;
    unsigned lo = f2bf(m_s[rr][c]), hi = f2bf(m_s[rr + 1][c]);
    *(unsigned*)(msgT + (size_t)c*N_AGENTS + r0 + rr) = lo | (hi << 16);
  }
}

// ---------------- Kernel B: adj @ msg partials, LDS-staged A, no atomics ----
// Block: 4 waves share a 32-row x 256-col A tile staged via global_load_lds
// (contiguous 1 KB per instruction). Wave wv computes K sub-range wv*64 of each
// chunk; after 8 chunks each wave stores its own partial P[sliceGrp*4+wv].
// mfma_f32_16x16x32_bf16 layouts (verified R1): A[m=lane&15][k=(lane>>4)*8+j],
// B[k=(lane>>4)*8+j][n=lane&15], C/D: col=lane&15, row=(lane>>4)*4+reg.
__device__ __forceinline__ bf16x8 adj_frag(f32x4 lo, f32x4 hi) {
  union { bf16x8 v; unsigned u[4]; } r;
  r.u[0] = (lo.x < THRESH ? 0x3F80u : 0u) | (lo.y < THRESH ? 0x3F800000u : 0u);
  r.u[1] = (lo.z < THRESH ? 0x3F80u : 0u) | (lo.w < THRESH ? 0x3F800000u : 0u);
  r.u[2] = (hi.x < THRESH ? 0x3F80u : 0u) | (hi.y < THRESH ? 0x3F800000u : 0u);
  r.u[3] = (hi.z < THRESH ? 0x3F80u : 0u) | (hi.w < THRESH ? 0x3F800000u : 0u);
  return r.v;
}

__global__ __launch_bounds__(256, 4) void k_agg(
    const float* __restrict__ dists, const unsigned short* __restrict__ msgT,
    float* __restrict__ P)
{
  __shared__ __align__(16) float ldsA[32 * ROWSTRIDE];   // 33,280 B
  const int lane = threadIdx.x & 63;
  const int wv   = threadIdx.x >> 6;
  const int rowTile  = blockIdx.x & 255;        // 256 row tiles of 32
  const int sliceGrp = blockIdx.x >> 8;         // 0..3 -> K range of 2048
  const int row0 = rowTile * 32;
  const int kblk = sliceGrp * 2048;
  const int m = lane & 15, q = lane >> 4;

  f32x4 acc[2][4];
  #pragma unroll
  for (int g = 0; g < 2; ++g)
    #pragma unroll
    for (int nt = 0; nt < 4; ++nt) acc[g][nt] = (f32x4)0.0f;

  const unsigned short* bbase = msgT + (size_t)m * N_AGENTS;

  for (int chunk = 0; chunk < 8; ++chunk) {     // 8 chunks of 256 K
    const int kb = kblk + chunk * 256;
    // stage: wave wv stages rows wv*8..wv*8+7, 1 KB contiguous per instruction
    #pragma unroll
    for (int rr = 0; rr < 8; ++rr) {
      const int r = wv * 8 + rr;
      stage16(dists + (size_t)(row0 + r) * N_AGENTS + kb + lane * 4,
              &ldsA[r * ROWSTRIDE]);
    }
    __syncthreads();                            // drains vmcnt (staging) for all waves

    #pragma unroll
    for (int ks = 0; ks < 2; ++ks) {            // wave's 64-wide K sub-range
      const int kf = wv * 64 + ks * 32 + q * 8; // float offset within chunk
      f32x4 a00 = *(const f32x4*)&ldsA[m * ROWSTRIDE + kf];
      f32x4 a01 = *(const f32x4*)&ldsA[m * ROWSTRIDE + kf + 4];
      f32x4 a10 = *(const f32x4*)&ldsA[(m + 16) * ROWSTRIDE + kf];
      f32x4 a11 = *(const f32x4*)&ldsA[(m + 16) * ROWSTRIDE + kf + 4];
      bf16x8 af0 = adj_frag(a00, a01);
      bf16x8 af1 = adj_frag(a10, a11);
      const size_t kg = (size_t)kb + kf;
      bf16x8 b0 = *(const bf16x8*)(bbase + (size_t)0  * N_AGENTS + kg);
      bf16x8 b1 = *(const bf16x8*)(bbase + (size_t)16 * N_AGENTS + kg);
      bf16x8 b2 = *(const bf16x8*)(bbase + (size_t)32 * N_AGENTS + kg);
      bf16x8 b3 = *(const bf16x8*)(bbase + (size_t)48 * N_AGENTS + kg);
      acc[0][0] = __builtin_amdgcn_mfma_f32_16x16x32_bf16(af0, b0, acc[0][0], 0, 0, 0);
      acc[0][1] = __builtin_amdgcn_mfma_f32_16x16x32_bf16(af0, b1, acc[0][1], 0, 0, 0);
      acc[0][2] = __builtin_amdgcn_mfma_f32_16x16x32_bf16(af0, b2, acc[0][2], 0, 0, 0);
      acc[0][3] = __builtin_amdgcn_mfma_f32_16x16x32_bf16(af0, b3, acc[0][3], 0, 0, 0);
      acc[1][0] = __builtin_amdgcn_mfma_f32_16x16x32_bf16(af1, b0, acc[1][0], 0, 0, 0);
      acc[1][1] = __builtin_amdgcn_mfma_f32_16x16x32_bf16(af1, b1, acc[1][1], 0, 0, 0);
      acc[1][2] = __builtin_amdgcn_mfma_f32_16x16x32_bf16(af1, b2, acc[1][2], 0, 0, 0);
      acc[1][3] = __builtin_amdgcn_mfma_f32_16x16x32_bf16(af1, b3, acc[1][3], 0, 0, 0);
    }
    __syncthreads();                            // protect LDS before next stage
  }

  // per-wave partial store (plain dword stores, 64 B coalesced per 16-lane group)
  float* dst = P + (size_t)(sliceGrp * 4 + wv) * N_AGENTS * MSG;
  #pragma unroll
  for (int g = 0; g < 2; ++g)
    #pragma unroll
    for (int nt = 0; nt < 4; ++nt)
      #pragma unroll
      for (int r = 0; r < 4; ++r)
        dst[(size_t)(row0 + g*16 + q*4 + r) * MSG + nt*16 + m] = acc[g][nt][r];
}

// ---------------- Kernel C: epilogue — partial sum, diag fix, MLP, gumbel softmax ----
__global__ __launch_bounds__(256) void k_out(
    const float* __restrict__ P, const float* __restrict__ dists,
    const unsigned short* __restrict__ msgR,
    const float* __restrict__ h_in,
    const float* __restrict__ updW, const float* __restrict__ updB,
    const float* __restrict__ outW, const float* __restrict__ outB,
    const float* __restrict__ tau, float* __restrict__ out)
{
  __shared__ float x_s[4][CONCAT];
  __shared__ float h2_s[4][HIDDEN];
  const int w    = threadIdx.x >> 6;
  const int lane = threadIdx.x & 63;
  const int i    = blockIdx.x * 4 + w;

  float agg = 0.0f;
  #pragma unroll
  for (int g = 0; g < NPART; ++g)
    agg += P[((size_t)g * N_AGENTS + i) * MSG + lane];

  float dii = dists[(size_t)i * (N_AGENTS + 1)];
  if (dii < THRESH) { // remove diagonal contribution (adj has zero diagonal)
    unsigned short us = msgR[(size_t)i * MSG + lane];
    agg -= __uint_as_float(((unsigned)us) << 16);
  }

  x_s[w][HIDDEN + lane] = agg;
  if (lane < HIDDEN) x_s[w][lane] = h_in[(size_t)i * HIDDEN + lane];
  __syncthreads();

  if (lane < HIDDEN) {
    float acc = updB[lane];
    #pragma unroll
    for (int k = 0; k < CONCAT; ++k) acc = fmaf(x_s[w][k], updW[k*HIDDEN + lane], acc);
    h2_s[w][lane] = fmaxf(acc, 0.0f);
  }
  __syncthreads();

  float lg = outB[lane];
  #pragma unroll
  for (int c = 0; c < HIDDEN; ++c) lg = fmaf(h2_s[w][c], outW[c*MSG + lane], lg);

  float tv = (lg + gumbel_at((unsigned)i*64u + (unsigned)lane)) / tau[0];

  float mx = tv;
  #pragma unroll
  for (int off = 32; off > 0; off >>= 1) mx = fmaxf(mx, __shfl_xor(mx, off, 64));
  float ex = expf(tv - mx);
  float sm = ex;
  #pragma unroll
  for (int off = 32; off > 0; off >>= 1) sm += __shfl_xor(sm, off, 64);
  out[(size_t)i * MSG + lane] = ex / sm;
}

extern "C" void kernel_launch(void* const* d_in, const int* in_sizes, int n_in,
                              void* d_out, int out_size, void* d_ws, size_t ws_size,
                              hipStream_t stream) {
  const float* z     = (const float*)d_in[0];
  const float* tau   = (const float*)d_in[1];
  const float* dists = (const float*)d_in[2];
  const float* encW  = (const float*)d_in[3];
  const float* encB  = (const float*)d_in[4];
  const float* msgW  = (const float*)d_in[5];
  const float* msgB  = (const float*)d_in[6];
  const float* updW  = (const float*)d_in[7];
  const float* updB  = (const float*)d_in[8];
  const float* outW  = (const float*)d_in[9];
  const float* outB  = (const float*)d_in[10];
  (void)in_sizes; (void)n_in; (void)out_size; (void)ws_size;

  char* ws = (char*)d_ws;
  float*          P_ws  = (float*)(ws);                      // 16*8192*64*4 = 32 MB
  float*          h_ws  = (float*)(ws + (32u<<20));          // 8192*32*4    = 1 MB
  unsigned short* msgR  = (unsigned short*)(ws + (33u<<20)); // 8192*64*2    = 1 MB
  unsigned short* msgT  = (unsigned short*)(ws + (34u<<20)); // 64*8192*2    = 1 MB
  float* out = (float*)d_out;

  hipLaunchKernelGGL(k_encode, dim3(N_AGENTS/8), dim3(256), 0, stream,
                     z, encW, encB, msgW, msgB, h_ws, (unsigned*)msgR, msgT);
  hipLaunchKernelGGL(k_agg, dim3(256 * 4), dim3(256), 0, stream,
                     dists, msgT, P_ws);
  hipLaunchKernelGGL(k_out, dim3(N_AGENTS/4), dim3(256), 0, stream,
                     P_ws, dists, msgR, h_ws, updW, updB, outW, outB, tau, out);
}